// Round 1
// baseline (1699.955 us; speedup 1.0000x reference)
//
#include <hip/hip_runtime.h>
#include <hip/hip_cooperative_groups.h>
#include <math.h>

namespace cg = cooperative_groups;

#define IN_DIM 300
#define MEM 256
#define DEPTH 15
#define NNODES ((1 << (DEPTH + 1)) - 1)   // 65535
#define KX 320     // x-GEMM K (300 padded)
#define KH 256     // h-GEMM K
#define NKX 10     // KX/32
#define NKH 8      // KH/32
#define SX 328     // LDS row stride bf16
#define SH 264     // LDS row stride bf16

typedef __attribute__((ext_vector_type(8))) __bf16 bf16x8;
typedef __attribute__((ext_vector_type(4))) float f32x4;

__device__ __forceinline__ float sigmoidf_(float x) { return 1.0f / (1.0f + __expf(-x)); }
__device__ __forceinline__ float tanhfast_(float x) {
    return 1.0f - 2.0f / (__expf(2.0f * x) + 1.0f);
}
__device__ __forceinline__ f32x4 mfma_bf16(bf16x8 a, bf16x8 b, f32x4 acc) {
    return __builtin_amdgcn_mfma_f32_16x16x32_bf16(a, b, acc, 0, 0, 0);
}

// Fragment-linear B layout: elem(cb, ks, lane, e) at ((cb*NK + ks)*64 + lane)*8 + e,
// holding W[col = cb*16 + (lane&15)][k = ks*32 + (lane>>4)*8 + e].
#define WTXF_ELEMS (64 * NKX * 512)   // 327680  (cols 0..767 = W_ioux, 768..1023 = W_fx)
#define WTHF_ELEMS (64 * NKH * 512)   // 262144  (cols 0..767 = W_iouh, 768..1023 = W_fh)

__global__ void prep_weights(const float* __restrict__ W_ioux, const float* __restrict__ W_fx,
                             const float* __restrict__ W_iouh, const float* __restrict__ W_fh,
                             __bf16* __restrict__ ws) {
    int idx = blockIdx.x * 256 + threadIdx.x;
    if (idx < WTXF_ELEMS) {
        int e = idx & 7, ln = (idx >> 3) & 63;
        int r = idx >> 9;             // 0..639
        int ks = r % NKX, cb = r / NKX;
        int col = cb * 16 + (ln & 15);
        int k = ks * 32 + (ln >> 4) * 8 + e;
        float v = 0.f;
        if (k < IN_DIM)
            v = (col < 768) ? W_ioux[col * IN_DIM + k] : W_fx[(col - 768) * IN_DIM + k];
        ws[idx] = (__bf16)v;
    } else if (idx < WTXF_ELEMS + WTHF_ELEMS) {
        int t = idx - WTXF_ELEMS;
        int e = t & 7, ln = (t >> 3) & 63;
        int r = t >> 9;               // 0..511
        int ks = r & 7, cb = r >> 3;
        int col = cb * 16 + (ln & 15);
        int k = ks * 32 + (ln >> 4) * 8 + e;
        float v = (col < 768) ? W_iouh[col * MEM + k] : W_fh[(col - 768) * MEM + k];
        ws[WTXF_ELEMS + t] = (__bf16)v;
    }
}

// Merged-accumulator tile body. Per-lane accs: iou 48 + fL 16 + fR 16 = 80 f32
// (MT=4), fitting the 128-reg/wave cap of a 16-wave block WITHOUT spilling.
// h-GEMMs run first (iou-h into aI/aO/aU, W_fh·hl into aL, W_fh·hr into aR),
// then the x-GEMM accumulates on top (iou-x into aI/aO/aU, W_fx·x into BOTH
// aL and aR — fx folded, no separate fx accumulator).
template <int MT, bool LEAF>
__device__ __forceinline__ void tile_body(
    const float* __restrict__ x_in,
    const __bf16* __restrict__ wtx, const __bf16* __restrict__ wth,
    const float* __restrict__ b_ioux, const float* __restrict__ b_iouh,
    const float* __restrict__ b_fx, const float* __restrict__ b_fh,
    float* __restrict__ c, float* __restrict__ h,
    int node0, int mcount, __bf16* Xs, __bf16* Hlr, __bf16* Hsum)
{
    constexpr int NT = MT * 16;
    const int tid = threadIdx.x;
    const int w = tid >> 6, l = tid & 63, lc = l & 15, q = l >> 4;
    const int childbase = 2 * node0 + 1;

    // ---- stage X ----
    for (int t = tid; t < NT * (KX / 8); t += 1024) {
        int m = t / (KX / 8), kc = t - m * (KX / 8), k = kc * 8;
        float4 v0 = {0.f, 0.f, 0.f, 0.f}, v1 = {0.f, 0.f, 0.f, 0.f};
        if (m < mcount) {
            const float* row = x_in + (size_t)(node0 + m) * IN_DIM;
            if (k + 8 <= IN_DIM) { v0 = *(const float4*)(row + k); v1 = *(const float4*)(row + k + 4); }
            else if (k == 296)   { v0 = *(const float4*)(row + k); }   // 296..299 valid
        }
        bf16x8 pk;
        pk[0] = (__bf16)v0.x; pk[1] = (__bf16)v0.y; pk[2] = (__bf16)v0.z; pk[3] = (__bf16)v0.w;
        pk[4] = (__bf16)v1.x; pk[5] = (__bf16)v1.y; pk[6] = (__bf16)v1.z; pk[7] = (__bf16)v1.w;
        *(bf16x8*)&Xs[m * SX + k] = pk;
    }
    // ---- stage children h (de-interleaved) + hsum ----
    if constexpr (!LEAF) {
        for (int t = tid; t < NT * (KH / 8); t += 1024) {
            int m = t >> 5, kc = t & 31, k = kc * 8;
            float4 l0 = {0.f,0.f,0.f,0.f}, l1 = l0, r0 = l0, r1 = l0;
            if (m < mcount) {
                const float4* lp = (const float4*)(h + (size_t)(childbase + 2 * m) * MEM + k);
                const float4* rp = (const float4*)(h + (size_t)(childbase + 2 * m + 1) * MEM + k);
                l0 = lp[0]; l1 = lp[1]; r0 = rp[0]; r1 = rp[1];
            }
            bf16x8 pl, pr, ps;
            pl[0]=(__bf16)l0.x; pl[1]=(__bf16)l0.y; pl[2]=(__bf16)l0.z; pl[3]=(__bf16)l0.w;
            pl[4]=(__bf16)l1.x; pl[5]=(__bf16)l1.y; pl[6]=(__bf16)l1.z; pl[7]=(__bf16)l1.w;
            pr[0]=(__bf16)r0.x; pr[1]=(__bf16)r0.y; pr[2]=(__bf16)r0.z; pr[3]=(__bf16)r0.w;
            pr[4]=(__bf16)r1.x; pr[5]=(__bf16)r1.y; pr[6]=(__bf16)r1.z; pr[7]=(__bf16)r1.w;
            ps[0]=(__bf16)(l0.x+r0.x); ps[1]=(__bf16)(l0.y+r0.y);
            ps[2]=(__bf16)(l0.z+r0.z); ps[3]=(__bf16)(l0.w+r0.w);
            ps[4]=(__bf16)(l1.x+r1.x); ps[5]=(__bf16)(l1.y+r1.y);
            ps[6]=(__bf16)(l1.z+r1.z); ps[7]=(__bf16)(l1.w+r1.w);
            *(bf16x8*)&Hlr[m * SH + k] = pl;
            *(bf16x8*)&Hlr[(NT + m) * SH + k] = pr;
            *(bf16x8*)&Hsum[m * SH + k] = ps;
        }
    }
    __syncthreads();

    const f32x4 z4 = {0.f, 0.f, 0.f, 0.f};
    f32x4 aI[MT], aO[MT], aU[MT], aL[MT], aR[MT];
#pragma unroll
    for (int mt = 0; mt < MT; ++mt) {
        aI[mt] = z4; aO[mt] = z4; aU[mt] = z4;
        if constexpr (!LEAF) { aL[mt] = z4; aR[mt] = z4; }
    }

    // ---- h-path GEMMs (first) ----
    if constexpr (!LEAF) {
        const __bf16* b0 = wth + ((size_t)(w)      * NKH) * 512 + l * 8;
        const __bf16* b1 = wth + ((size_t)(16 + w) * NKH) * 512 + l * 8;
        const __bf16* b2 = wth + ((size_t)(32 + w) * NKH) * 512 + l * 8;
        const __bf16* bF = wth + ((size_t)(48 + w) * NKH) * 512 + l * 8;
        for (int ks = 0; ks < NKH; ++ks) {
            bf16x8 vb0 = *(const bf16x8*)(b0 + ks * 512);
            bf16x8 vb1 = *(const bf16x8*)(b1 + ks * 512);
            bf16x8 vb2 = *(const bf16x8*)(b2 + ks * 512);
            bf16x8 vbf = *(const bf16x8*)(bF + ks * 512);
            const int ko = ks * 32 + q * 8;
#pragma unroll
            for (int mt = 0; mt < MT; ++mt) {
                bf16x8 as = *(const bf16x8*)&Hsum[(mt * 16 + lc) * SH + ko];
                bf16x8 al = *(const bf16x8*)&Hlr[(mt * 16 + lc) * SH + ko];
                bf16x8 ar = *(const bf16x8*)&Hlr[(NT + mt * 16 + lc) * SH + ko];
                aI[mt] = mfma_bf16(as, vb0, aI[mt]);
                aO[mt] = mfma_bf16(as, vb1, aO[mt]);
                aU[mt] = mfma_bf16(as, vb2, aU[mt]);
                aL[mt] = mfma_bf16(al, vbf, aL[mt]);
                aR[mt] = mfma_bf16(ar, vbf, aR[mt]);
            }
        }
    }

    // ---- x-path GEMM (accumulates into the same regs) ----
    {
        const __bf16* bx0 = wtx + ((size_t)(w)      * NKX) * 512 + l * 8;
        const __bf16* bx1 = wtx + ((size_t)(16 + w) * NKX) * 512 + l * 8;
        const __bf16* bx2 = wtx + ((size_t)(32 + w) * NKX) * 512 + l * 8;
        const __bf16* bxF = wtx + ((size_t)(48 + w) * NKX) * 512 + l * 8;
        for (int ks = 0; ks < NKX; ++ks) {
            bf16x8 vb0 = *(const bf16x8*)(bx0 + ks * 512);
            bf16x8 vb1 = *(const bf16x8*)(bx1 + ks * 512);
            bf16x8 vb2 = *(const bf16x8*)(bx2 + ks * 512);
            bf16x8 vbf;
            if constexpr (!LEAF) vbf = *(const bf16x8*)(bxF + ks * 512);
            const int ko = ks * 32 + q * 8;
#pragma unroll
            for (int mt = 0; mt < MT; ++mt) {
                bf16x8 ax = *(const bf16x8*)&Xs[(mt * 16 + lc) * SX + ko];
                aI[mt] = mfma_bf16(ax, vb0, aI[mt]);
                aO[mt] = mfma_bf16(ax, vb1, aO[mt]);
                aU[mt] = mfma_bf16(ax, vb2, aU[mt]);
                if constexpr (!LEAF) {
                    aL[mt] = mfma_bf16(ax, vbf, aL[mt]);   // fx folded into fL
                    aR[mt] = mfma_bf16(ax, vbf, aR[mt]);   // fx folded into fR
                }
            }
        }
    }

    // ---- lane-local epilogue (C/D: col = lane&15, row = 4*(lane>>4) + reg) ----
    const int jj = w * 16 + lc;
    const float bi = b_ioux[jj]       + b_iouh[jj];
    const float bo = b_ioux[256 + jj] + b_iouh[256 + jj];
    const float bu = b_ioux[512 + jj] + b_iouh[512 + jj];
    float bff = 0.f;
    if constexpr (!LEAF) bff = b_fx[jj] + b_fh[jj];

#pragma unroll
    for (int mt = 0; mt < MT; ++mt) {
#pragma unroll
        for (int r = 0; r < 4; ++r) {
            const int n = mt * 16 + q * 4 + r;
            const float iv = sigmoidf_(aI[mt][r] + bi);
            const float ov = sigmoidf_(aO[mt][r] + bo);
            const float uv = tanhfast_(aU[mt][r] + bu);
            float cn;
            if constexpr (!LEAF) {
                const float fl = sigmoidf_(aL[mt][r] + bff);
                const float fr = sigmoidf_(aR[mt][r] + bff);
                float cl = 0.f, cr = 0.f;
                if (n < mcount) {
                    cl = c[(size_t)(childbase + 2 * n) * MEM + jj];
                    cr = c[(size_t)(childbase + 2 * n + 1) * MEM + jj];
                }
                cn = iv * uv + fl * cl + fr * cr;
            } else {
                cn = iv * uv;
            }
            const float hn = ov * tanhfast_(cn);
            if (n < mcount) {
                c[(size_t)(node0 + n) * MEM + jj] = cn;
                h[(size_t)(node0 + n) * MEM + jj] = hn;
            }
        }
    }
}

template <int MT, bool LEAF, int MINW>
__global__ __launch_bounds__(1024, MINW) void level_mfma(
    const float* __restrict__ x_in,
    const __bf16* __restrict__ wtx, const __bf16* __restrict__ wth,
    const float* __restrict__ b_ioux, const float* __restrict__ b_iouh,
    const float* __restrict__ b_fx, const float* __restrict__ b_fh,
    float* __restrict__ c, float* __restrict__ h,
    int start, int levsize)
{
    constexpr int NT = MT * 16;
    __shared__ __align__(16) __bf16 Xs[NT * SX];
    __shared__ __align__(16) __bf16 Hlr[LEAF ? 8 : 2 * NT * SH];
    __shared__ __align__(16) __bf16 Hsum[LEAF ? 8 : NT * SH];
    const int tile0 = blockIdx.x * NT;
    tile_body<MT, LEAF>(x_in, wtx, wth, b_ioux, b_iouh, b_fx, b_fh, c, h,
                        start + tile0, min(NT, levsize - tile0), Xs, Hlr, Hsum);
}

// Fused tail: levels d = 12..0 in ONE cooperative kernel, MT=1 tiles,
// 256 blocks x 1024 threads (1 block/CU co-resident), grid.sync between levels.
__global__ __launch_bounds__(1024, 4) void tree_tail(
    const float* __restrict__ x_in,
    const __bf16* __restrict__ wtx, const __bf16* __restrict__ wth,
    const float* __restrict__ b_ioux, const float* __restrict__ b_iouh,
    const float* __restrict__ b_fx, const float* __restrict__ b_fh,
    float* __restrict__ c, float* __restrict__ h)
{
    __shared__ __align__(16) __bf16 Xs[16 * SX];
    __shared__ __align__(16) __bf16 Hlr[2 * 16 * SH];
    __shared__ __align__(16) __bf16 Hsum[16 * SH];
    cg::grid_group grid = cg::this_grid();
    for (int d = 12; d >= 0; --d) {
        const int start = (1 << d) - 1, sz = 1 << d;
        const int tiles = (sz + 15) >> 4;
        if ((int)blockIdx.x < tiles) {
            const int tile0 = blockIdx.x * 16;
            tile_body<1, false>(x_in, wtx, wth, b_ioux, b_iouh, b_fx, b_fh, c, h,
                                start + tile0, min(16, sz - tile0), Xs, Hlr, Hsum);
        }
        if (d > 0) {
            __threadfence();
            grid.sync();
        }
    }
}

extern "C" void kernel_launch(void* const* d_in, const int* in_sizes, int n_in,
                              void* d_out, int out_size, void* d_ws, size_t ws_size,
                              hipStream_t stream) {
    const float* inputs = (const float*)d_in[0];
    const float* W_ioux = (const float*)d_in[1];
    const float* b_ioux = (const float*)d_in[2];
    const float* W_iouh = (const float*)d_in[3];
    const float* b_iouh = (const float*)d_in[4];
    const float* W_fx   = (const float*)d_in[5];
    const float* b_fx   = (const float*)d_in[6];
    const float* W_fh   = (const float*)d_in[7];
    const float* b_fh   = (const float*)d_in[8];

    float* out = (float*)d_out;
    float* c = out;
    float* h = out + (size_t)NNODES * MEM;

    __bf16* wtx = (__bf16*)d_ws;
    __bf16* wth = wtx + WTXF_ELEMS;

    {
        int total = WTXF_ELEMS + WTHF_ELEMS;
        hipLaunchKernelGGL(prep_weights, dim3((total + 255) / 256), dim3(256),
                           0, stream, W_ioux, W_fx, W_iouh, W_fh, (__bf16*)d_ws);
    }

    // d = 15 (leaves), d = 14, d = 13: 64-node blocks (B-stream amortized 4x)
    hipLaunchKernelGGL((level_mfma<4, true, 4>), dim3(512), dim3(1024), 0, stream,
                       inputs, wtx, wth, b_ioux, b_iouh, b_fx, b_fh, c, h,
                       (1 << 15) - 1, 1 << 15);
    hipLaunchKernelGGL((level_mfma<4, false, 4>), dim3(256), dim3(1024), 0, stream,
                       inputs, wtx, wth, b_ioux, b_iouh, b_fx, b_fh, c, h,
                       (1 << 14) - 1, 1 << 14);
    hipLaunchKernelGGL((level_mfma<4, false, 4>), dim3(128), dim3(1024), 0, stream,
                       inputs, wtx, wth, b_ioux, b_iouh, b_fx, b_fh, c, h,
                       (1 << 13) - 1, 1 << 13);

    // d <= 12: single cooperative kernel, grid-synced between levels
    {
        void* args[] = {(void*)&inputs, (void*)&wtx, (void*)&wth,
                        (void*)&b_ioux, (void*)&b_iouh, (void*)&b_fx, (void*)&b_fh,
                        (void*)&c, (void*)&h};
        hipLaunchCooperativeKernel((void*)tree_tail, dim3(256), dim3(1024), args, 0, stream);
    }
}

// Round 2
// 817.056 us; speedup vs baseline: 2.0806x; 2.0806x over previous
//
#include <hip/hip_runtime.h>
#include <math.h>

#define IN_DIM 300
#define MEM 256
#define DEPTH 15
#define NNODES ((1 << (DEPTH + 1)) - 1)   // 65535
#define KX 320     // x-GEMM K (300 padded)
#define KH 256     // h-GEMM K
#define NKX 10     // KX/32
#define NKH 8      // KH/32
#define SX 328     // LDS row stride bf16
#define SH 264     // LDS row stride bf16

typedef __attribute__((ext_vector_type(8))) __bf16 bf16x8;
typedef __attribute__((ext_vector_type(4))) float f32x4;

__device__ __forceinline__ float sigmoidf_(float x) { return 1.0f / (1.0f + __expf(-x)); }
__device__ __forceinline__ float tanhfast_(float x) {
    return 1.0f - 2.0f / (__expf(2.0f * x) + 1.0f);
}
__device__ __forceinline__ f32x4 mfma_bf16(bf16x8 a, bf16x8 b, f32x4 acc) {
    return __builtin_amdgcn_mfma_f32_16x16x32_bf16(a, b, acc, 0, 0, 0);
}

// Fragment-linear B layout: elem(cb, ks, lane, e) at ((cb*NK + ks)*64 + lane)*8 + e,
// holding W[col = cb*16 + (lane&15)][k = ks*32 + (lane>>4)*8 + e].
#define WTXF_ELEMS (64 * NKX * 512)   // 327680  (cols 0..767 = W_ioux, 768..1023 = W_fx)
#define WTHF_ELEMS (64 * NKH * 512)   // 262144  (cols 0..767 = W_iouh, 768..1023 = W_fh)

__global__ void prep_weights(const float* __restrict__ W_ioux, const float* __restrict__ W_fx,
                             const float* __restrict__ W_iouh, const float* __restrict__ W_fh,
                             __bf16* __restrict__ ws) {
    int idx = blockIdx.x * 256 + threadIdx.x;
    if (idx < WTXF_ELEMS) {
        int e = idx & 7, ln = (idx >> 3) & 63;
        int r = idx >> 9;             // 0..639
        int ks = r % NKX, cb = r / NKX;
        int col = cb * 16 + (ln & 15);
        int k = ks * 32 + (ln >> 4) * 8 + e;
        float v = 0.f;
        if (k < IN_DIM)
            v = (col < 768) ? W_ioux[col * IN_DIM + k] : W_fx[(col - 768) * IN_DIM + k];
        ws[idx] = (__bf16)v;
    } else if (idx < WTXF_ELEMS + WTHF_ELEMS) {
        int t = idx - WTXF_ELEMS;
        int e = t & 7, ln = (t >> 3) & 63;
        int r = t >> 9;               // 0..511
        int ks = r & 7, cb = r >> 3;
        int col = cb * 16 + (ln & 15);
        int k = ks * 32 + (ln >> 4) * 8 + e;
        float v = (col < 768) ? W_iouh[col * MEM + k] : W_fh[(col - 768) * MEM + k];
        ws[WTXF_ELEMS + t] = (__bf16)v;
    }
}

// Merged-accumulator tile body. Per-lane accs: iou 48 + fL 16 + fR 16 = 80 f32
// (MT=4), fitting the 128-reg/wave cap of a 16-wave block WITHOUT spilling.
// h-GEMMs run first (iou-h into aI/aO/aU, W_fh·hl into aL, W_fh·hr into aR),
// then the x-GEMM accumulates on top (iou-x into aI/aO/aU, W_fx·x into BOTH
// aL and aR — fx folded, no separate fx accumulator).
template <int MT, bool LEAF>
__device__ __forceinline__ void tile_body(
    const float* __restrict__ x_in,
    const __bf16* __restrict__ wtx, const __bf16* __restrict__ wth,
    const float* __restrict__ b_ioux, const float* __restrict__ b_iouh,
    const float* __restrict__ b_fx, const float* __restrict__ b_fh,
    float* __restrict__ c, float* __restrict__ h,
    int node0, int mcount, __bf16* Xs, __bf16* Hlr, __bf16* Hsum)
{
    constexpr int NT = MT * 16;
    const int tid = threadIdx.x;
    const int w = tid >> 6, l = tid & 63, lc = l & 15, q = l >> 4;
    const int childbase = 2 * node0 + 1;

    // ---- stage X ----
    for (int t = tid; t < NT * (KX / 8); t += 1024) {
        int m = t / (KX / 8), kc = t - m * (KX / 8), k = kc * 8;
        float4 v0 = {0.f, 0.f, 0.f, 0.f}, v1 = {0.f, 0.f, 0.f, 0.f};
        if (m < mcount) {
            const float* row = x_in + (size_t)(node0 + m) * IN_DIM;
            if (k + 8 <= IN_DIM) { v0 = *(const float4*)(row + k); v1 = *(const float4*)(row + k + 4); }
            else if (k == 296)   { v0 = *(const float4*)(row + k); }   // 296..299 valid
        }
        bf16x8 pk;
        pk[0] = (__bf16)v0.x; pk[1] = (__bf16)v0.y; pk[2] = (__bf16)v0.z; pk[3] = (__bf16)v0.w;
        pk[4] = (__bf16)v1.x; pk[5] = (__bf16)v1.y; pk[6] = (__bf16)v1.z; pk[7] = (__bf16)v1.w;
        *(bf16x8*)&Xs[m * SX + k] = pk;
    }
    // ---- stage children h (de-interleaved) + hsum ----
    if constexpr (!LEAF) {
        for (int t = tid; t < NT * (KH / 8); t += 1024) {
            int m = t >> 5, kc = t & 31, k = kc * 8;
            float4 l0 = {0.f,0.f,0.f,0.f}, l1 = l0, r0 = l0, r1 = l0;
            if (m < mcount) {
                const float4* lp = (const float4*)(h + (size_t)(childbase + 2 * m) * MEM + k);
                const float4* rp = (const float4*)(h + (size_t)(childbase + 2 * m + 1) * MEM + k);
                l0 = lp[0]; l1 = lp[1]; r0 = rp[0]; r1 = rp[1];
            }
            bf16x8 pl, pr, ps;
            pl[0]=(__bf16)l0.x; pl[1]=(__bf16)l0.y; pl[2]=(__bf16)l0.z; pl[3]=(__bf16)l0.w;
            pl[4]=(__bf16)l1.x; pl[5]=(__bf16)l1.y; pl[6]=(__bf16)l1.z; pl[7]=(__bf16)l1.w;
            pr[0]=(__bf16)r0.x; pr[1]=(__bf16)r0.y; pr[2]=(__bf16)r0.z; pr[3]=(__bf16)r0.w;
            pr[4]=(__bf16)r1.x; pr[5]=(__bf16)r1.y; pr[6]=(__bf16)r1.z; pr[7]=(__bf16)r1.w;
            ps[0]=(__bf16)(l0.x+r0.x); ps[1]=(__bf16)(l0.y+r0.y);
            ps[2]=(__bf16)(l0.z+r0.z); ps[3]=(__bf16)(l0.w+r0.w);
            ps[4]=(__bf16)(l1.x+r1.x); ps[5]=(__bf16)(l1.y+r1.y);
            ps[6]=(__bf16)(l1.z+r1.z); ps[7]=(__bf16)(l1.w+r1.w);
            *(bf16x8*)&Hlr[m * SH + k] = pl;
            *(bf16x8*)&Hlr[(NT + m) * SH + k] = pr;
            *(bf16x8*)&Hsum[m * SH + k] = ps;
        }
    }
    __syncthreads();

    const f32x4 z4 = {0.f, 0.f, 0.f, 0.f};
    f32x4 aI[MT], aO[MT], aU[MT], aL[MT], aR[MT];
#pragma unroll
    for (int mt = 0; mt < MT; ++mt) {
        aI[mt] = z4; aO[mt] = z4; aU[mt] = z4;
        if constexpr (!LEAF) { aL[mt] = z4; aR[mt] = z4; }
    }

    // ---- h-path GEMMs (first) ----
    if constexpr (!LEAF) {
        const __bf16* b0 = wth + ((size_t)(w)      * NKH) * 512 + l * 8;
        const __bf16* b1 = wth + ((size_t)(16 + w) * NKH) * 512 + l * 8;
        const __bf16* b2 = wth + ((size_t)(32 + w) * NKH) * 512 + l * 8;
        const __bf16* bF = wth + ((size_t)(48 + w) * NKH) * 512 + l * 8;
        for (int ks = 0; ks < NKH; ++ks) {
            bf16x8 vb0 = *(const bf16x8*)(b0 + ks * 512);
            bf16x8 vb1 = *(const bf16x8*)(b1 + ks * 512);
            bf16x8 vb2 = *(const bf16x8*)(b2 + ks * 512);
            bf16x8 vbf = *(const bf16x8*)(bF + ks * 512);
            const int ko = ks * 32 + q * 8;
#pragma unroll
            for (int mt = 0; mt < MT; ++mt) {
                bf16x8 as = *(const bf16x8*)&Hsum[(mt * 16 + lc) * SH + ko];
                bf16x8 al = *(const bf16x8*)&Hlr[(mt * 16 + lc) * SH + ko];
                bf16x8 ar = *(const bf16x8*)&Hlr[(NT + mt * 16 + lc) * SH + ko];
                aI[mt] = mfma_bf16(as, vb0, aI[mt]);
                aO[mt] = mfma_bf16(as, vb1, aO[mt]);
                aU[mt] = mfma_bf16(as, vb2, aU[mt]);
                aL[mt] = mfma_bf16(al, vbf, aL[mt]);
                aR[mt] = mfma_bf16(ar, vbf, aR[mt]);
            }
        }
    }

    // ---- x-path GEMM (accumulates into the same regs) ----
    {
        const __bf16* bx0 = wtx + ((size_t)(w)      * NKX) * 512 + l * 8;
        const __bf16* bx1 = wtx + ((size_t)(16 + w) * NKX) * 512 + l * 8;
        const __bf16* bx2 = wtx + ((size_t)(32 + w) * NKX) * 512 + l * 8;
        const __bf16* bxF = wtx + ((size_t)(48 + w) * NKX) * 512 + l * 8;
        for (int ks = 0; ks < NKX; ++ks) {
            bf16x8 vb0 = *(const bf16x8*)(bx0 + ks * 512);
            bf16x8 vb1 = *(const bf16x8*)(bx1 + ks * 512);
            bf16x8 vb2 = *(const bf16x8*)(bx2 + ks * 512);
            bf16x8 vbf;
            if constexpr (!LEAF) vbf = *(const bf16x8*)(bxF + ks * 512);
            const int ko = ks * 32 + q * 8;
#pragma unroll
            for (int mt = 0; mt < MT; ++mt) {
                bf16x8 ax = *(const bf16x8*)&Xs[(mt * 16 + lc) * SX + ko];
                aI[mt] = mfma_bf16(ax, vb0, aI[mt]);
                aO[mt] = mfma_bf16(ax, vb1, aO[mt]);
                aU[mt] = mfma_bf16(ax, vb2, aU[mt]);
                if constexpr (!LEAF) {
                    aL[mt] = mfma_bf16(ax, vbf, aL[mt]);   // fx folded into fL
                    aR[mt] = mfma_bf16(ax, vbf, aR[mt]);   // fx folded into fR
                }
            }
        }
    }

    // ---- lane-local epilogue (C/D: col = lane&15, row = 4*(lane>>4) + reg) ----
    const int jj = w * 16 + lc;
    const float bi = b_ioux[jj]       + b_iouh[jj];
    const float bo = b_ioux[256 + jj] + b_iouh[256 + jj];
    const float bu = b_ioux[512 + jj] + b_iouh[512 + jj];
    float bff = 0.f;
    if constexpr (!LEAF) bff = b_fx[jj] + b_fh[jj];

#pragma unroll
    for (int mt = 0; mt < MT; ++mt) {
#pragma unroll
        for (int r = 0; r < 4; ++r) {
            const int n = mt * 16 + q * 4 + r;
            const float iv = sigmoidf_(aI[mt][r] + bi);
            const float ov = sigmoidf_(aO[mt][r] + bo);
            const float uv = tanhfast_(aU[mt][r] + bu);
            float cn;
            if constexpr (!LEAF) {
                const float fl = sigmoidf_(aL[mt][r] + bff);
                const float fr = sigmoidf_(aR[mt][r] + bff);
                float cl = 0.f, cr = 0.f;
                if (n < mcount) {
                    cl = c[(size_t)(childbase + 2 * n) * MEM + jj];
                    cr = c[(size_t)(childbase + 2 * n + 1) * MEM + jj];
                }
                cn = iv * uv + fl * cl + fr * cr;
            } else {
                cn = iv * uv;
            }
            const float hn = ov * tanhfast_(cn);
            if (n < mcount) {
                c[(size_t)(node0 + n) * MEM + jj] = cn;
                h[(size_t)(node0 + n) * MEM + jj] = hn;
            }
        }
    }
}

template <int MT, bool LEAF, int MINW>
__global__ __launch_bounds__(1024, MINW) void level_mfma(
    const float* __restrict__ x_in,
    const __bf16* __restrict__ wtx, const __bf16* __restrict__ wth,
    const float* __restrict__ b_ioux, const float* __restrict__ b_iouh,
    const float* __restrict__ b_fx, const float* __restrict__ b_fh,
    float* __restrict__ c, float* __restrict__ h,
    int start, int levsize)
{
    constexpr int NT = MT * 16;
    __shared__ __align__(16) __bf16 Xs[NT * SX];
    __shared__ __align__(16) __bf16 Hlr[LEAF ? 8 : 2 * NT * SH];
    __shared__ __align__(16) __bf16 Hsum[LEAF ? 8 : NT * SH];
    const int tile0 = blockIdx.x * NT;
    tile_body<MT, LEAF>(x_in, wtx, wth, b_ioux, b_iouh, b_fx, b_fh, c, h,
                        start + tile0, min(NT, levsize - tile0), Xs, Hlr, Hsum);
}

// Fused small-level tail: levels d = 6..0 (127 nodes total) in ONE single-block
// kernel. Every level fits one MT=4 tile (<= 64 nodes), so one block owns the
// entire level and inter-level deps only need __syncthreads (same CU, global
// RAW is coherent through L1/L2 once the barrier drains vmcnt).
__global__ __launch_bounds__(1024, 4) void tail_small(
    const float* __restrict__ x_in,
    const __bf16* __restrict__ wtx, const __bf16* __restrict__ wth,
    const float* __restrict__ b_ioux, const float* __restrict__ b_iouh,
    const float* __restrict__ b_fx, const float* __restrict__ b_fh,
    float* __restrict__ c, float* __restrict__ h)
{
    __shared__ __align__(16) __bf16 Xs[64 * SX];
    __shared__ __align__(16) __bf16 Hlr[2 * 64 * SH];
    __shared__ __align__(16) __bf16 Hsum[64 * SH];
    for (int d = 6; d >= 0; --d) {
        const int start = (1 << d) - 1, sz = 1 << d;
        tile_body<4, false>(x_in, wtx, wth, b_ioux, b_iouh, b_fx, b_fh, c, h,
                            start, sz, Xs, Hlr, Hsum);
        __threadfence_block();
        __syncthreads();   // all waves done (LDS reads + c/h writes) before restage
    }
}

extern "C" void kernel_launch(void* const* d_in, const int* in_sizes, int n_in,
                              void* d_out, int out_size, void* d_ws, size_t ws_size,
                              hipStream_t stream) {
    const float* inputs = (const float*)d_in[0];
    const float* W_ioux = (const float*)d_in[1];
    const float* b_ioux = (const float*)d_in[2];
    const float* W_iouh = (const float*)d_in[3];
    const float* b_iouh = (const float*)d_in[4];
    const float* W_fx   = (const float*)d_in[5];
    const float* b_fx   = (const float*)d_in[6];
    const float* W_fh   = (const float*)d_in[7];
    const float* b_fh   = (const float*)d_in[8];

    float* out = (float*)d_out;
    float* c = out;
    float* h = out + (size_t)NNODES * MEM;

    __bf16* wtx = (__bf16*)d_ws;
    __bf16* wth = wtx + WTXF_ELEMS;

    {
        int total = WTXF_ELEMS + WTHF_ELEMS;
        hipLaunchKernelGGL(prep_weights, dim3((total + 255) / 256), dim3(256),
                           0, stream, W_ioux, W_fx, W_iouh, W_fh, (__bf16*)d_ws);
    }

    // d = 15 (leaves), d = 14, d = 13: 64-node blocks (B-stream amortized 4x)
    hipLaunchKernelGGL((level_mfma<4, true, 4>), dim3(512), dim3(1024), 0, stream,
                       inputs, wtx, wth, b_ioux, b_iouh, b_fx, b_fh, c, h,
                       (1 << 15) - 1, 1 << 15);
    hipLaunchKernelGGL((level_mfma<4, false, 4>), dim3(256), dim3(1024), 0, stream,
                       inputs, wtx, wth, b_ioux, b_iouh, b_fx, b_fh, c, h,
                       (1 << 14) - 1, 1 << 14);
    hipLaunchKernelGGL((level_mfma<4, false, 4>), dim3(128), dim3(1024), 0, stream,
                       inputs, wtx, wth, b_ioux, b_iouh, b_fx, b_fh, c, h,
                       (1 << 13) - 1, 1 << 13);
    // d = 12..7: 16-node blocks, one launch per level
    for (int d = 12; d >= 7; --d) {
        int start = (1 << d) - 1;
        int sz = 1 << d;
        int blocks = (sz + 15) / 16;
        hipLaunchKernelGGL((level_mfma<1, false, 4>), dim3(blocks), dim3(1024), 0, stream,
                           inputs, wtx, wth, b_ioux, b_iouh, b_fx, b_fh, c, h,
                           start, sz);
    }
    // d = 6..0: single-block fused kernel (127 nodes, 7 levels, no grid sync)
    hipLaunchKernelGGL(tail_small, dim3(1), dim3(1024), 0, stream,
                       inputs, wtx, wth, b_ioux, b_iouh, b_fx, b_fh, c, h);
}

// Round 4
// 552.005 us; speedup vs baseline: 3.0796x; 1.4802x over previous
//
#include <hip/hip_runtime.h>
#include <math.h>

#define IN_DIM 300
#define MEM 256
#define DEPTH 15
#define NNODES ((1 << (DEPTH + 1)) - 1)   // 65535
#define KX 320     // x-GEMM K (300 padded)
#define KH 256     // h-GEMM K
#define NKX 10     // KX/32
#define NKH 8      // KH/32
#define SX 328     // LDS row stride bf16
#define SH 264     // LDS row stride bf16
#define NT 32      // nodes per tile (2 x 16-row MFMA sub-tiles)

typedef __attribute__((ext_vector_type(8))) __bf16 bf16x8;
typedef __attribute__((ext_vector_type(4))) float f32x4;

__device__ __forceinline__ float sigmoidf_(float x) { return 1.0f / (1.0f + __expf(-x)); }
__device__ __forceinline__ float tanhfast_(float x) {
    return 1.0f - 2.0f / (__expf(2.0f * x) + 1.0f);
}
__device__ __forceinline__ f32x4 mfma_bf16(bf16x8 a, bf16x8 b, f32x4 acc) {
    return __builtin_amdgcn_mfma_f32_16x16x32_bf16(a, b, acc, 0, 0, 0);
}

// Fragment-linear B layout: elem(cb, ks, lane, e) at ((cb*NK + ks)*64 + lane)*8 + e,
// holding W[col = cb*16 + (lane&15)][k = ks*32 + (lane>>4)*8 + e].
#define WTXF_ELEMS (64 * NKX * 512)   // 327680  (cols 0..767 = W_ioux, 768..1023 = W_fx)
#define WTHF_ELEMS (64 * NKH * 512)   // 262144  (cols 0..767 = W_iouh, 768..1023 = W_fh)

__global__ void prep_weights(const float* __restrict__ W_ioux, const float* __restrict__ W_fx,
                             const float* __restrict__ W_iouh, const float* __restrict__ W_fh,
                             __bf16* __restrict__ ws) {
    int idx = blockIdx.x * 256 + threadIdx.x;
    if (idx < WTXF_ELEMS) {
        int e = idx & 7, ln = (idx >> 3) & 63;
        int r = idx >> 9;             // 0..639
        int ks = r % NKX, cb = r / NKX;
        int col = cb * 16 + (ln & 15);
        int k = ks * 32 + (ln >> 4) * 8 + e;
        float v = 0.f;
        if (k < IN_DIM)
            v = (col < 768) ? W_ioux[col * IN_DIM + k] : W_fx[(col - 768) * IN_DIM + k];
        ws[idx] = (__bf16)v;
    } else if (idx < WTXF_ELEMS + WTHF_ELEMS) {
        int t = idx - WTXF_ELEMS;
        int e = t & 7, ln = (t >> 3) & 63;
        int r = t >> 9;               // 0..511
        int ks = r & 7, cb = r >> 3;
        int col = cb * 16 + (ln & 15);
        int k = ks * 32 + (ln >> 4) * 8 + e;
        float v = (col < 768) ? W_iouh[col * MEM + k] : W_fh[(col - 768) * MEM + k];
        ws[WTXF_ELEMS + t] = (__bf16)v;
    }
}

// 512-thread / 8-wave tile. Wave w owns TWO 16-col slices (s0=2w, s1=2w+1) of
// every gate group -> 8 B-streams, acc = 2 slices x {i,o,u,fL,fR} x 2 subtiles
// x 4 = 80 f32. An 8-wave block runs at 2 waves/SIMD, so the register budget
// is 256/wave: accs + operands fit WITHOUT spilling (1024-thread blocks are
// hard-capped at 128/wave -> the acc array spilled every K-iter; that was the
// 154 MB of excess WRITE_SIZE and MfmaUtil=7%).
template <bool LEAF>
__device__ __forceinline__ void tile_body(
    const float* __restrict__ x_in,
    const __bf16* __restrict__ wtx, const __bf16* __restrict__ wth,
    const float* __restrict__ b_ioux, const float* __restrict__ b_iouh,
    const float* __restrict__ b_fx, const float* __restrict__ b_fh,
    float* __restrict__ c, float* __restrict__ h,
    int node0, int mcount, __bf16* Xs, __bf16* Hlr, __bf16* Hsum)
{
    const int tid = threadIdx.x;               // 0..511
    const int w = tid >> 6, l = tid & 63, lc = l & 15, q = l >> 4;
    const int childbase = 2 * node0 + 1;

    // ---- stage X ----
    for (int t = tid; t < NT * (KX / 8); t += 512) {
        int m = t / (KX / 8), kc = t - m * (KX / 8), k = kc * 8;
        float4 v0 = {0.f, 0.f, 0.f, 0.f}, v1 = {0.f, 0.f, 0.f, 0.f};
        if (m < mcount) {
            const float* row = x_in + (size_t)(node0 + m) * IN_DIM;
            if (k + 8 <= IN_DIM) { v0 = *(const float4*)(row + k); v1 = *(const float4*)(row + k + 4); }
            else if (k == 296)   { v0 = *(const float4*)(row + k); }   // 296..299 valid
        }
        bf16x8 pk;
        pk[0] = (__bf16)v0.x; pk[1] = (__bf16)v0.y; pk[2] = (__bf16)v0.z; pk[3] = (__bf16)v0.w;
        pk[4] = (__bf16)v1.x; pk[5] = (__bf16)v1.y; pk[6] = (__bf16)v1.z; pk[7] = (__bf16)v1.w;
        *(bf16x8*)&Xs[m * SX + k] = pk;
    }
    // ---- stage children h (de-interleaved) + hsum ----
    if constexpr (!LEAF) {
        for (int t = tid; t < NT * (KH / 8); t += 512) {
            int m = t >> 5, kc = t & 31, k = kc * 8;
            float4 l0 = {0.f,0.f,0.f,0.f}, l1 = l0, r0 = l0, r1 = l0;
            if (m < mcount) {
                const float4* lp = (const float4*)(h + (size_t)(childbase + 2 * m) * MEM + k);
                const float4* rp = (const float4*)(h + (size_t)(childbase + 2 * m + 1) * MEM + k);
                l0 = lp[0]; l1 = lp[1]; r0 = rp[0]; r1 = rp[1];
            }
            bf16x8 pl, pr, ps;
            pl[0]=(__bf16)l0.x; pl[1]=(__bf16)l0.y; pl[2]=(__bf16)l0.z; pl[3]=(__bf16)l0.w;
            pl[4]=(__bf16)l1.x; pl[5]=(__bf16)l1.y; pl[6]=(__bf16)l1.z; pl[7]=(__bf16)l1.w;
            pr[0]=(__bf16)r0.x; pr[1]=(__bf16)r0.y; pr[2]=(__bf16)r0.z; pr[3]=(__bf16)r0.w;
            pr[4]=(__bf16)r1.x; pr[5]=(__bf16)r1.y; pr[6]=(__bf16)r1.z; pr[7]=(__bf16)r1.w;
            ps[0]=(__bf16)(l0.x+r0.x); ps[1]=(__bf16)(l0.y+r0.y);
            ps[2]=(__bf16)(l0.z+r0.z); ps[3]=(__bf16)(l0.w+r0.w);
            ps[4]=(__bf16)(l1.x+r1.x); ps[5]=(__bf16)(l1.y+r1.y);
            ps[6]=(__bf16)(l1.z+r1.z); ps[7]=(__bf16)(l1.w+r1.w);
            *(bf16x8*)&Hlr[m * SH + k] = pl;
            *(bf16x8*)&Hlr[(NT + m) * SH + k] = pr;
            *(bf16x8*)&Hsum[m * SH + k] = ps;
        }
    }
    __syncthreads();

    const f32x4 z4 = {0.f, 0.f, 0.f, 0.f};
    f32x4 aI[2][2], aO[2][2], aU[2][2], aL[2][2], aR[2][2];
#pragma unroll
    for (int s = 0; s < 2; ++s)
#pragma unroll
        for (int mt = 0; mt < 2; ++mt) {
            aI[s][mt] = z4; aO[s][mt] = z4; aU[s][mt] = z4;
            if constexpr (!LEAF) { aL[s][mt] = z4; aR[s][mt] = z4; }
        }

    const int s0 = 2 * w, s1 = 2 * w + 1;

    // ---- h-path GEMMs (first) ----
    if constexpr (!LEAF) {
        const __bf16* pi0 = wth + ((size_t)(s0)      * NKH) * 512 + l * 8;
        const __bf16* pi1 = wth + ((size_t)(s1)      * NKH) * 512 + l * 8;
        const __bf16* po0 = wth + ((size_t)(16 + s0) * NKH) * 512 + l * 8;
        const __bf16* po1 = wth + ((size_t)(16 + s1) * NKH) * 512 + l * 8;
        const __bf16* pu0 = wth + ((size_t)(32 + s0) * NKH) * 512 + l * 8;
        const __bf16* pu1 = wth + ((size_t)(32 + s1) * NKH) * 512 + l * 8;
        const __bf16* pf0 = wth + ((size_t)(48 + s0) * NKH) * 512 + l * 8;
        const __bf16* pf1 = wth + ((size_t)(48 + s1) * NKH) * 512 + l * 8;
        for (int ks = 0; ks < NKH; ++ks) {
            bf16x8 vi0 = *(const bf16x8*)(pi0 + ks * 512);
            bf16x8 vi1 = *(const bf16x8*)(pi1 + ks * 512);
            bf16x8 vo0 = *(const bf16x8*)(po0 + ks * 512);
            bf16x8 vo1 = *(const bf16x8*)(po1 + ks * 512);
            bf16x8 vu0 = *(const bf16x8*)(pu0 + ks * 512);
            bf16x8 vu1 = *(const bf16x8*)(pu1 + ks * 512);
            bf16x8 vf0 = *(const bf16x8*)(pf0 + ks * 512);
            bf16x8 vf1 = *(const bf16x8*)(pf1 + ks * 512);
            const int ko = ks * 32 + q * 8;
#pragma unroll
            for (int mt = 0; mt < 2; ++mt) {
                bf16x8 as = *(const bf16x8*)&Hsum[(mt * 16 + lc) * SH + ko];
                bf16x8 al = *(const bf16x8*)&Hlr[(mt * 16 + lc) * SH + ko];
                bf16x8 ar = *(const bf16x8*)&Hlr[(NT + mt * 16 + lc) * SH + ko];
                aI[0][mt] = mfma_bf16(as, vi0, aI[0][mt]);
                aI[1][mt] = mfma_bf16(as, vi1, aI[1][mt]);
                aO[0][mt] = mfma_bf16(as, vo0, aO[0][mt]);
                aO[1][mt] = mfma_bf16(as, vo1, aO[1][mt]);
                aU[0][mt] = mfma_bf16(as, vu0, aU[0][mt]);
                aU[1][mt] = mfma_bf16(as, vu1, aU[1][mt]);
                aL[0][mt] = mfma_bf16(al, vf0, aL[0][mt]);
                aL[1][mt] = mfma_bf16(al, vf1, aL[1][mt]);
                aR[0][mt] = mfma_bf16(ar, vf0, aR[0][mt]);
                aR[1][mt] = mfma_bf16(ar, vf1, aR[1][mt]);
            }
        }
    }

    // ---- x-path GEMM (accumulates into the same regs; fx folded into fL/fR) ----
    {
        const __bf16* pi0 = wtx + ((size_t)(s0)      * NKX) * 512 + l * 8;
        const __bf16* pi1 = wtx + ((size_t)(s1)      * NKX) * 512 + l * 8;
        const __bf16* po0 = wtx + ((size_t)(16 + s0) * NKX) * 512 + l * 8;
        const __bf16* po1 = wtx + ((size_t)(16 + s1) * NKX) * 512 + l * 8;
        const __bf16* pu0 = wtx + ((size_t)(32 + s0) * NKX) * 512 + l * 8;
        const __bf16* pu1 = wtx + ((size_t)(32 + s1) * NKX) * 512 + l * 8;
        const __bf16* pf0 = wtx + ((size_t)(48 + s0) * NKX) * 512 + l * 8;
        const __bf16* pf1 = wtx + ((size_t)(48 + s1) * NKX) * 512 + l * 8;
        for (int ks = 0; ks < NKX; ++ks) {
            bf16x8 vi0 = *(const bf16x8*)(pi0 + ks * 512);
            bf16x8 vi1 = *(const bf16x8*)(pi1 + ks * 512);
            bf16x8 vo0 = *(const bf16x8*)(po0 + ks * 512);
            bf16x8 vo1 = *(const bf16x8*)(po1 + ks * 512);
            bf16x8 vu0 = *(const bf16x8*)(pu0 + ks * 512);
            bf16x8 vu1 = *(const bf16x8*)(pu1 + ks * 512);
            bf16x8 vf0, vf1;
            if constexpr (!LEAF) {
                vf0 = *(const bf16x8*)(pf0 + ks * 512);
                vf1 = *(const bf16x8*)(pf1 + ks * 512);
            }
            const int ko = ks * 32 + q * 8;
#pragma unroll
            for (int mt = 0; mt < 2; ++mt) {
                bf16x8 ax = *(const bf16x8*)&Xs[(mt * 16 + lc) * SX + ko];
                aI[0][mt] = mfma_bf16(ax, vi0, aI[0][mt]);
                aI[1][mt] = mfma_bf16(ax, vi1, aI[1][mt]);
                aO[0][mt] = mfma_bf16(ax, vo0, aO[0][mt]);
                aO[1][mt] = mfma_bf16(ax, vo1, aO[1][mt]);
                aU[0][mt] = mfma_bf16(ax, vu0, aU[0][mt]);
                aU[1][mt] = mfma_bf16(ax, vu1, aU[1][mt]);
                if constexpr (!LEAF) {
                    aL[0][mt] = mfma_bf16(ax, vf0, aL[0][mt]);
                    aR[0][mt] = mfma_bf16(ax, vf0, aR[0][mt]);
                    aL[1][mt] = mfma_bf16(ax, vf1, aL[1][mt]);
                    aR[1][mt] = mfma_bf16(ax, vf1, aR[1][mt]);
                }
            }
        }
    }

    // ---- lane-local epilogue (C/D: col = lane&15, row = 4*(lane>>4) + reg) ----
#pragma unroll
    for (int s = 0; s < 2; ++s) {
        const int jj = (2 * w + s) * 16 + lc;
        const float bi = b_ioux[jj]       + b_iouh[jj];
        const float bo = b_ioux[256 + jj] + b_iouh[256 + jj];
        const float bu = b_ioux[512 + jj] + b_iouh[512 + jj];
        float bff = 0.f;
        if constexpr (!LEAF) bff = b_fx[jj] + b_fh[jj];
#pragma unroll
        for (int mt = 0; mt < 2; ++mt) {
#pragma unroll
            for (int r = 0; r < 4; ++r) {
                const int n = mt * 16 + q * 4 + r;
                const float iv = sigmoidf_(aI[s][mt][r] + bi);
                const float ov = sigmoidf_(aO[s][mt][r] + bo);
                const float uv = tanhfast_(aU[s][mt][r] + bu);
                float cn;
                if constexpr (!LEAF) {
                    const float fl = sigmoidf_(aL[s][mt][r] + bff);
                    const float fr = sigmoidf_(aR[s][mt][r] + bff);
                    float cl = 0.f, cr = 0.f;
                    if (n < mcount) {
                        cl = c[(size_t)(childbase + 2 * n) * MEM + jj];
                        cr = c[(size_t)(childbase + 2 * n + 1) * MEM + jj];
                    }
                    cn = iv * uv + fl * cl + fr * cr;
                } else {
                    cn = iv * uv;
                }
                const float hn = ov * tanhfast_(cn);
                if (n < mcount) {
                    c[(size_t)(node0 + n) * MEM + jj] = cn;
                    h[(size_t)(node0 + n) * MEM + jj] = hn;
                }
            }
        }
    }
}

template <bool LEAF, int MINW>
__global__ __launch_bounds__(512, MINW) void level_mfma(
    const float* __restrict__ x_in,
    const __bf16* __restrict__ wtx, const __bf16* __restrict__ wth,
    const float* __restrict__ b_ioux, const float* __restrict__ b_iouh,
    const float* __restrict__ b_fx, const float* __restrict__ b_fh,
    float* __restrict__ c, float* __restrict__ h,
    int start, int levsize)
{
    __shared__ __align__(16) __bf16 Xs[NT * SX];
    __shared__ __align__(16) __bf16 Hlr[LEAF ? 8 : 2 * NT * SH];
    __shared__ __align__(16) __bf16 Hsum[LEAF ? 8 : NT * SH];
    const int tile0 = blockIdx.x * NT;
    tile_body<LEAF>(x_in, wtx, wth, b_ioux, b_iouh, b_fx, b_fh, c, h,
                    start + tile0, min(NT, levsize - tile0), Xs, Hlr, Hsum);
}

// Fused small-level tail: levels d = 6..0 (127 nodes total) in ONE single-block
// kernel (no grid sync; same-CU global RAW is ordered by the vmcnt drain at
// each __syncthreads). d=6 runs two sequential 32-node tiles.
__global__ __launch_bounds__(512, 2) void tail_small(
    const float* __restrict__ x_in,
    const __bf16* __restrict__ wtx, const __bf16* __restrict__ wth,
    const float* __restrict__ b_ioux, const float* __restrict__ b_iouh,
    const float* __restrict__ b_fx, const float* __restrict__ b_fh,
    float* __restrict__ c, float* __restrict__ h)
{
    __shared__ __align__(16) __bf16 Xs[NT * SX];
    __shared__ __align__(16) __bf16 Hlr[2 * NT * SH];
    __shared__ __align__(16) __bf16 Hsum[NT * SH];
    for (int d = 6; d >= 0; --d) {
        const int start = (1 << d) - 1, sz = 1 << d;
        for (int t0 = 0; t0 < sz; t0 += NT) {
            tile_body<false>(x_in, wtx, wth, b_ioux, b_iouh, b_fx, b_fh, c, h,
                             start + t0, min(NT, sz - t0), Xs, Hlr, Hsum);
            __threadfence_block();
            __syncthreads();   // LDS reads + c/h writes drained before restage
        }
    }
}

extern "C" void kernel_launch(void* const* d_in, const int* in_sizes, int n_in,
                              void* d_out, int out_size, void* d_ws, size_t ws_size,
                              hipStream_t stream) {
    const float* inputs = (const float*)d_in[0];
    const float* W_ioux = (const float*)d_in[1];
    const float* b_ioux = (const float*)d_in[2];
    const float* W_iouh = (const float*)d_in[3];
    const float* b_iouh = (const float*)d_in[4];
    const float* W_fx   = (const float*)d_in[5];
    const float* b_fx   = (const float*)d_in[6];
    const float* W_fh   = (const float*)d_in[7];
    const float* b_fh   = (const float*)d_in[8];

    float* out = (float*)d_out;
    float* c = out;
    float* h = out + (size_t)NNODES * MEM;

    __bf16* wtx = (__bf16*)d_ws;
    __bf16* wth = wtx + WTXF_ELEMS;

    {
        int total = WTXF_ELEMS + WTHF_ELEMS;
        hipLaunchKernelGGL(prep_weights, dim3((total + 255) / 256), dim3(256),
                           0, stream, W_ioux, W_fx, W_iouh, W_fh, (__bf16*)d_ws);
    }

    // d = 15 (leaves): 48 accs -> fits 128-reg budget, 2 blocks/CU
    hipLaunchKernelGGL((level_mfma<true, 4>), dim3(1024), dim3(512), 0, stream,
                       inputs, wtx, wth, b_ioux, b_iouh, b_fx, b_fh, c, h,
                       (1 << 15) - 1, 1 << 15);
    // d = 14, 13: 80 accs -> needs 256-reg budget (8-wave block, 2/SIMD)
    hipLaunchKernelGGL((level_mfma<false, 2>), dim3(512), dim3(512), 0, stream,
                       inputs, wtx, wth, b_ioux, b_iouh, b_fx, b_fh, c, h,
                       (1 << 14) - 1, 1 << 14);
    hipLaunchKernelGGL((level_mfma<false, 2>), dim3(256), dim3(512), 0, stream,
                       inputs, wtx, wth, b_ioux, b_iouh, b_fx, b_fh, c, h,
                       (1 << 13) - 1, 1 << 13);
    // d = 12..7: one launch per level, 32-node blocks
    for (int d = 12; d >= 7; --d) {
        int start = (1 << d) - 1;
        int sz = 1 << d;
        int blocks = (sz + NT - 1) / NT;
        hipLaunchKernelGGL((level_mfma<false, 2>), dim3(blocks), dim3(512), 0, stream,
                           inputs, wtx, wth, b_ioux, b_iouh, b_fx, b_fh, c, h,
                           start, sz);
    }
    // d = 6..0: single-block fused kernel (127 nodes, 7 levels)
    hipLaunchKernelGGL(tail_small, dim3(1), dim3(512), 0, stream,
                       inputs, wtx, wth, b_ioux, b_iouh, b_fx, b_fh, c, h);
}

// Round 6
// 420.577 us; speedup vs baseline: 4.0420x; 1.3125x over previous
//
#include <hip/hip_runtime.h>
#include <math.h>

#define IN_DIM 300
#define MEM 256
#define DEPTH 15
#define NNODES ((1 << (DEPTH + 1)) - 1)   // 65535
#define KX 320     // x-GEMM K (300 padded)
#define KH 256     // h-GEMM K
#define NKX 10     // KX/32
#define NKH 8      // KH/32
#define SX 328     // LDS row stride bf16
#define SH 264     // LDS row stride bf16
#define NT 32      // nodes per tile (2 x 16-row MFMA sub-tiles)
#define RSTR 41    // reduce-buffer lane stride (odd -> conflict-free)

typedef __attribute__((ext_vector_type(8))) __bf16 bf16x8;
typedef __attribute__((ext_vector_type(4))) float f32x4;

__device__ __forceinline__ float sigmoidf_(float x) { return 1.0f / (1.0f + __expf(-x)); }
__device__ __forceinline__ float tanhfast_(float x) {
    return 1.0f - 2.0f / (__expf(2.0f * x) + 1.0f);
}
__device__ __forceinline__ f32x4 mfma_bf16(bf16x8 a, bf16x8 b, f32x4 acc) {
    return __builtin_amdgcn_mfma_f32_16x16x32_bf16(a, b, acc, 0, 0, 0);
}

// Fragment-linear B layout: elem(cb, ks, lane, e) at ((cb*NK + ks)*64 + lane)*8 + e,
// holding W[col = cb*16 + (lane&15)][k = ks*32 + (lane>>4)*8 + e].
#define WTXF_ELEMS (64 * NKX * 512)   // 327680  (cols 0..767 = W_ioux, 768..1023 = W_fx)
#define WTHF_ELEMS (64 * NKH * 512)   // 262144  (cols 0..767 = W_iouh, 768..1023 = W_fh)

__global__ void prep_weights(const float* __restrict__ W_ioux, const float* __restrict__ W_fx,
                             const float* __restrict__ W_iouh, const float* __restrict__ W_fh,
                             __bf16* __restrict__ ws) {
    int idx = blockIdx.x * 256 + threadIdx.x;
    if (idx < WTXF_ELEMS) {
        int e = idx & 7, ln = (idx >> 3) & 63;
        int r = idx >> 9;             // 0..639
        int ks = r % NKX, cb = r / NKX;
        int col = cb * 16 + (ln & 15);
        int k = ks * 32 + (ln >> 4) * 8 + e;
        float v = 0.f;
        if (k < IN_DIM)
            v = (col < 768) ? W_ioux[col * IN_DIM + k] : W_fx[(col - 768) * IN_DIM + k];
        ws[idx] = (__bf16)v;
    } else if (idx < WTXF_ELEMS + WTHF_ELEMS) {
        int t = idx - WTXF_ELEMS;
        int e = t & 7, ln = (t >> 3) & 63;
        int r = t >> 9;               // 0..511
        int ks = r & 7, cb = r >> 3;
        int col = cb * 16 + (ln & 15);
        int k = ks * 32 + (ln >> 4) * 8 + e;
        float v = (col < 768) ? W_iouh[col * MEM + k] : W_fh[(col - 768) * MEM + k];
        ws[WTXF_ELEMS + t] = (__bf16)v;
    }
}

// ---- shared staging helpers (512 threads) ----
__device__ __forceinline__ void stage_x(const float* __restrict__ x_in, __bf16* Xs,
                                        int node0, int mcount) {
    for (int t = threadIdx.x; t < NT * (KX / 8); t += 512) {
        int m = t / (KX / 8), kc = t - m * (KX / 8), k = kc * 8;
        float4 v0 = {0.f, 0.f, 0.f, 0.f}, v1 = {0.f, 0.f, 0.f, 0.f};
        if (m < mcount) {
            const float* row = x_in + (size_t)(node0 + m) * IN_DIM;
            if (k + 8 <= IN_DIM) { v0 = *(const float4*)(row + k); v1 = *(const float4*)(row + k + 4); }
            else if (k == 296)   { v0 = *(const float4*)(row + k); }   // 296..299 valid
        }
        bf16x8 pk;
        pk[0] = (__bf16)v0.x; pk[1] = (__bf16)v0.y; pk[2] = (__bf16)v0.z; pk[3] = (__bf16)v0.w;
        pk[4] = (__bf16)v1.x; pk[5] = (__bf16)v1.y; pk[6] = (__bf16)v1.z; pk[7] = (__bf16)v1.w;
        *(bf16x8*)&Xs[m * SX + k] = pk;
    }
}

__device__ __forceinline__ void stage_h(const float* __restrict__ h, __bf16* Hlr, __bf16* Hsum,
                                        int childbase, int mcount) {
    for (int t = threadIdx.x; t < NT * (KH / 8); t += 512) {
        int m = t >> 5, kc = t & 31, k = kc * 8;
        float4 l0 = {0.f,0.f,0.f,0.f}, l1 = l0, r0 = l0, r1 = l0;
        if (m < mcount) {
            const float4* lp = (const float4*)(h + (size_t)(childbase + 2 * m) * MEM + k);
            const float4* rp = (const float4*)(h + (size_t)(childbase + 2 * m + 1) * MEM + k);
            l0 = lp[0]; l1 = lp[1]; r0 = rp[0]; r1 = rp[1];
        }
        bf16x8 pl, pr, ps;
        pl[0]=(__bf16)l0.x; pl[1]=(__bf16)l0.y; pl[2]=(__bf16)l0.z; pl[3]=(__bf16)l0.w;
        pl[4]=(__bf16)l1.x; pl[5]=(__bf16)l1.y; pl[6]=(__bf16)l1.z; pl[7]=(__bf16)l1.w;
        pr[0]=(__bf16)r0.x; pr[1]=(__bf16)r0.y; pr[2]=(__bf16)r0.z; pr[3]=(__bf16)r0.w;
        pr[4]=(__bf16)r1.x; pr[5]=(__bf16)r1.y; pr[6]=(__bf16)r1.z; pr[7]=(__bf16)r1.w;
        ps[0]=(__bf16)(l0.x+r0.x); ps[1]=(__bf16)(l0.y+r0.y);
        ps[2]=(__bf16)(l0.z+r0.z); ps[3]=(__bf16)(l0.w+r0.w);
        ps[4]=(__bf16)(l1.x+r1.x); ps[5]=(__bf16)(l1.y+r1.y);
        ps[6]=(__bf16)(l1.z+r1.z); ps[7]=(__bf16)(l1.w+r1.w);
        *(bf16x8*)&Hlr[m * SH + k] = pl;
        *(bf16x8*)&Hlr[(NT + m) * SH + k] = pr;
        *(bf16x8*)&Hsum[m * SH + k] = ps;
    }
}

// 512-thread / 8-wave tile. Wave w owns TWO 16-col slices (s0=2w, s1=2w+1) of
// every gate group -> 8 B-streams, acc = 80 f32. 8-wave block = 2 waves/SIMD
// -> 256-reg budget: no spill (16-wave blocks cap at 128 regs and spilled).
template <bool LEAF>
__device__ __forceinline__ void tile_body(
    const float* __restrict__ x_in,
    const __bf16* __restrict__ wtx, const __bf16* __restrict__ wth,
    const float* __restrict__ b_ioux, const float* __restrict__ b_iouh,
    const float* __restrict__ b_fx, const float* __restrict__ b_fh,
    float* __restrict__ c, float* __restrict__ h,
    int node0, int mcount, __bf16* Xs, __bf16* Hlr, __bf16* Hsum)
{
    const int tid = threadIdx.x;               // 0..511
    const int w = tid >> 6, l = tid & 63, lc = l & 15, q = l >> 4;
    const int childbase = 2 * node0 + 1;

    stage_x(x_in, Xs, node0, mcount);
    if constexpr (!LEAF) stage_h(h, Hlr, Hsum, childbase, mcount);
    __syncthreads();

    const f32x4 z4 = {0.f, 0.f, 0.f, 0.f};
    f32x4 aI[2][2], aO[2][2], aU[2][2], aL[2][2], aR[2][2];
#pragma unroll
    for (int s = 0; s < 2; ++s)
#pragma unroll
        for (int mt = 0; mt < 2; ++mt) {
            aI[s][mt] = z4; aO[s][mt] = z4; aU[s][mt] = z4;
            if constexpr (!LEAF) { aL[s][mt] = z4; aR[s][mt] = z4; }
        }

    const int s0 = 2 * w, s1 = 2 * w + 1;

    if constexpr (!LEAF) {
        const __bf16* pi0 = wth + ((size_t)(s0)      * NKH) * 512 + l * 8;
        const __bf16* pi1 = wth + ((size_t)(s1)      * NKH) * 512 + l * 8;
        const __bf16* po0 = wth + ((size_t)(16 + s0) * NKH) * 512 + l * 8;
        const __bf16* po1 = wth + ((size_t)(16 + s1) * NKH) * 512 + l * 8;
        const __bf16* pu0 = wth + ((size_t)(32 + s0) * NKH) * 512 + l * 8;
        const __bf16* pu1 = wth + ((size_t)(32 + s1) * NKH) * 512 + l * 8;
        const __bf16* pf0 = wth + ((size_t)(48 + s0) * NKH) * 512 + l * 8;
        const __bf16* pf1 = wth + ((size_t)(48 + s1) * NKH) * 512 + l * 8;
        for (int ks = 0; ks < NKH; ++ks) {
            bf16x8 vi0 = *(const bf16x8*)(pi0 + ks * 512);
            bf16x8 vi1 = *(const bf16x8*)(pi1 + ks * 512);
            bf16x8 vo0 = *(const bf16x8*)(po0 + ks * 512);
            bf16x8 vo1 = *(const bf16x8*)(po1 + ks * 512);
            bf16x8 vu0 = *(const bf16x8*)(pu0 + ks * 512);
            bf16x8 vu1 = *(const bf16x8*)(pu1 + ks * 512);
            bf16x8 vf0 = *(const bf16x8*)(pf0 + ks * 512);
            bf16x8 vf1 = *(const bf16x8*)(pf1 + ks * 512);
            const int ko = ks * 32 + q * 8;
#pragma unroll
            for (int mt = 0; mt < 2; ++mt) {
                bf16x8 as = *(const bf16x8*)&Hsum[(mt * 16 + lc) * SH + ko];
                bf16x8 al = *(const bf16x8*)&Hlr[(mt * 16 + lc) * SH + ko];
                bf16x8 ar = *(const bf16x8*)&Hlr[(NT + mt * 16 + lc) * SH + ko];
                aI[0][mt] = mfma_bf16(as, vi0, aI[0][mt]);
                aI[1][mt] = mfma_bf16(as, vi1, aI[1][mt]);
                aO[0][mt] = mfma_bf16(as, vo0, aO[0][mt]);
                aO[1][mt] = mfma_bf16(as, vo1, aO[1][mt]);
                aU[0][mt] = mfma_bf16(as, vu0, aU[0][mt]);
                aU[1][mt] = mfma_bf16(as, vu1, aU[1][mt]);
                aL[0][mt] = mfma_bf16(al, vf0, aL[0][mt]);
                aL[1][mt] = mfma_bf16(al, vf1, aL[1][mt]);
                aR[0][mt] = mfma_bf16(ar, vf0, aR[0][mt]);
                aR[1][mt] = mfma_bf16(ar, vf1, aR[1][mt]);
            }
        }
    }

    {
        const __bf16* pi0 = wtx + ((size_t)(s0)      * NKX) * 512 + l * 8;
        const __bf16* pi1 = wtx + ((size_t)(s1)      * NKX) * 512 + l * 8;
        const __bf16* po0 = wtx + ((size_t)(16 + s0) * NKX) * 512 + l * 8;
        const __bf16* po1 = wtx + ((size_t)(16 + s1) * NKX) * 512 + l * 8;
        const __bf16* pu0 = wtx + ((size_t)(32 + s0) * NKX) * 512 + l * 8;
        const __bf16* pu1 = wtx + ((size_t)(32 + s1) * NKX) * 512 + l * 8;
        const __bf16* pf0 = wtx + ((size_t)(48 + s0) * NKX) * 512 + l * 8;
        const __bf16* pf1 = wtx + ((size_t)(48 + s1) * NKX) * 512 + l * 8;
        for (int ks = 0; ks < NKX; ++ks) {
            bf16x8 vi0 = *(const bf16x8*)(pi0 + ks * 512);
            bf16x8 vi1 = *(const bf16x8*)(pi1 + ks * 512);
            bf16x8 vo0 = *(const bf16x8*)(po0 + ks * 512);
            bf16x8 vo1 = *(const bf16x8*)(po1 + ks * 512);
            bf16x8 vu0 = *(const bf16x8*)(pu0 + ks * 512);
            bf16x8 vu1 = *(const bf16x8*)(pu1 + ks * 512);
            bf16x8 vf0, vf1;
            if constexpr (!LEAF) {
                vf0 = *(const bf16x8*)(pf0 + ks * 512);
                vf1 = *(const bf16x8*)(pf1 + ks * 512);
            }
            const int ko = ks * 32 + q * 8;
#pragma unroll
            for (int mt = 0; mt < 2; ++mt) {
                bf16x8 ax = *(const bf16x8*)&Xs[(mt * 16 + lc) * SX + ko];
                aI[0][mt] = mfma_bf16(ax, vi0, aI[0][mt]);
                aI[1][mt] = mfma_bf16(ax, vi1, aI[1][mt]);
                aO[0][mt] = mfma_bf16(ax, vo0, aO[0][mt]);
                aO[1][mt] = mfma_bf16(ax, vo1, aO[1][mt]);
                aU[0][mt] = mfma_bf16(ax, vu0, aU[0][mt]);
                aU[1][mt] = mfma_bf16(ax, vu1, aU[1][mt]);
                if constexpr (!LEAF) {
                    aL[0][mt] = mfma_bf16(ax, vf0, aL[0][mt]);
                    aR[0][mt] = mfma_bf16(ax, vf0, aR[0][mt]);
                    aL[1][mt] = mfma_bf16(ax, vf1, aL[1][mt]);
                    aR[1][mt] = mfma_bf16(ax, vf1, aR[1][mt]);
                }
            }
        }
    }

#pragma unroll
    for (int s = 0; s < 2; ++s) {
        const int jj = (2 * w + s) * 16 + lc;
        const float bi = b_ioux[jj]       + b_iouh[jj];
        const float bo = b_ioux[256 + jj] + b_iouh[256 + jj];
        const float bu = b_ioux[512 + jj] + b_iouh[512 + jj];
        float bff = 0.f;
        if constexpr (!LEAF) bff = b_fx[jj] + b_fh[jj];
#pragma unroll
        for (int mt = 0; mt < 2; ++mt) {
#pragma unroll
            for (int r = 0; r < 4; ++r) {
                const int n = mt * 16 + q * 4 + r;
                const float iv = sigmoidf_(aI[s][mt][r] + bi);
                const float ov = sigmoidf_(aO[s][mt][r] + bo);
                const float uv = tanhfast_(aU[s][mt][r] + bu);
                float cn;
                if constexpr (!LEAF) {
                    const float fl = sigmoidf_(aL[s][mt][r] + bff);
                    const float fr = sigmoidf_(aR[s][mt][r] + bff);
                    float cl = 0.f, cr = 0.f;
                    if (n < mcount) {
                        cl = c[(size_t)(childbase + 2 * n) * MEM + jj];
                        cr = c[(size_t)(childbase + 2 * n + 1) * MEM + jj];
                    }
                    cn = iv * uv + fl * cl + fr * cr;
                } else {
                    cn = iv * uv;
                }
                const float hn = ov * tanhfast_(cn);
                if (n < mcount) {
                    c[(size_t)(node0 + n) * MEM + jj] = cn;
                    h[(size_t)(node0 + n) * MEM + jj] = hn;
                }
            }
        }
    }
}

template <bool LEAF, int MINW>
__global__ __launch_bounds__(512, MINW) void level_mfma(
    const float* __restrict__ x_in,
    const __bf16* __restrict__ wtx, const __bf16* __restrict__ wth,
    const float* __restrict__ b_ioux, const float* __restrict__ b_iouh,
    const float* __restrict__ b_fx, const float* __restrict__ b_fh,
    float* __restrict__ c, float* __restrict__ h,
    int start, int levsize)
{
    __shared__ __align__(16) __bf16 Xs[NT * SX];
    __shared__ __align__(16) __bf16 Hlr[LEAF ? 8 : 2 * NT * SH];
    __shared__ __align__(16) __bf16 Hsum[LEAF ? 8 : NT * SH];
    const int tile0 = blockIdx.x * NT;
    tile_body<LEAF>(x_in, wtx, wth, b_ioux, b_iouh, b_fx, b_fh, c, h,
                    start + tile0, min(NT, levsize - tile0), Xs, Hlr, Hsum);
}

// Column-split level kernel for small levels (d <= 12). blockIdx.y = colgroup
// cg in [0,4): the block computes col-slices s = 4cg + (w&3) only -> per-block
// weight stream is 295 KB instead of 1.18 MB (the per-CU weight stream was the
// floor for every small level: 17.6 us/block at ~67 GB/s). 8 waves = 4 slices
// x 2 K-halves; K-half partials combine through a one-shot LDS reduce that
// aliases the staging buffers after a barrier.
__global__ __launch_bounds__(512, 2) void level_colsplit(
    const float* __restrict__ x_in,
    const __bf16* __restrict__ wtx, const __bf16* __restrict__ wth,
    const float* __restrict__ b_ioux, const float* __restrict__ b_iouh,
    const float* __restrict__ b_fx, const float* __restrict__ b_fh,
    float* __restrict__ c, float* __restrict__ h,
    int start, int levsize)
{
    __shared__ __align__(16) unsigned char smem[71680];
    __bf16* Xs   = (__bf16*)smem;                  // NT*SX*2   = 20992 B
    __bf16* Hlr  = (__bf16*)(smem + 20992);        // 2*NT*SH*2 = 33792 B
    __bf16* Hsum = (__bf16*)(smem + 54784);        // NT*SH*2   = 16896 B

    const int tid = threadIdx.x;
    const int w = tid >> 6, l = tid & 63, lc = l & 15, q = l >> 4;
    const int s_loc = w & 3, kg = w >> 2;
    const int s = blockIdx.y * 4 + s_loc;          // col-slice 0..15
    const int tile0 = blockIdx.x * NT;
    const int node0 = start + tile0;
    const int mcount = min(NT, levsize - tile0);
    const int childbase = 2 * node0 + 1;

    stage_x(x_in, Xs, node0, mcount);
    stage_h(h, Hlr, Hsum, childbase, mcount);
    __syncthreads();

    const f32x4 z4 = {0.f, 0.f, 0.f, 0.f};
    f32x4 aI[2], aO[2], aU[2], aL[2], aR[2];
#pragma unroll
    for (int mt = 0; mt < 2; ++mt) { aI[mt] = z4; aO[mt] = z4; aU[mt] = z4; aL[mt] = z4; aR[mt] = z4; }

    // ---- h-path GEMM, K-half kg: ks in [4kg, 4kg+4) ----
    {
        const __bf16* pi = wth + ((size_t)(s)      * NKH) * 512 + l * 8;
        const __bf16* po = wth + ((size_t)(16 + s) * NKH) * 512 + l * 8;
        const __bf16* pu = wth + ((size_t)(32 + s) * NKH) * 512 + l * 8;
        const __bf16* pf = wth + ((size_t)(48 + s) * NKH) * 512 + l * 8;
        for (int ks = kg * 4; ks < kg * 4 + 4; ++ks) {
            bf16x8 vi = *(const bf16x8*)(pi + ks * 512);
            bf16x8 vo = *(const bf16x8*)(po + ks * 512);
            bf16x8 vu = *(const bf16x8*)(pu + ks * 512);
            bf16x8 vf = *(const bf16x8*)(pf + ks * 512);
            const int ko = ks * 32 + q * 8;
#pragma unroll
            for (int mt = 0; mt < 2; ++mt) {
                bf16x8 as = *(const bf16x8*)&Hsum[(mt * 16 + lc) * SH + ko];
                bf16x8 al = *(const bf16x8*)&Hlr[(mt * 16 + lc) * SH + ko];
                bf16x8 ar = *(const bf16x8*)&Hlr[(NT + mt * 16 + lc) * SH + ko];
                aI[mt] = mfma_bf16(as, vi, aI[mt]);
                aO[mt] = mfma_bf16(as, vo, aO[mt]);
                aU[mt] = mfma_bf16(as, vu, aU[mt]);
                aL[mt] = mfma_bf16(al, vf, aL[mt]);
                aR[mt] = mfma_bf16(ar, vf, aR[mt]);
            }
        }
    }
    // ---- x-path GEMM, K-half kg: ks in [5kg, 5kg+5); fx folded into fL/fR ----
    {
        const __bf16* pi = wtx + ((size_t)(s)      * NKX) * 512 + l * 8;
        const __bf16* po = wtx + ((size_t)(16 + s) * NKX) * 512 + l * 8;
        const __bf16* pu = wtx + ((size_t)(32 + s) * NKX) * 512 + l * 8;
        const __bf16* pf = wtx + ((size_t)(48 + s) * NKX) * 512 + l * 8;
        for (int ks = kg * 5; ks < kg * 5 + 5; ++ks) {
            bf16x8 vi = *(const bf16x8*)(pi + ks * 512);
            bf16x8 vo = *(const bf16x8*)(po + ks * 512);
            bf16x8 vu = *(const bf16x8*)(pu + ks * 512);
            bf16x8 vf = *(const bf16x8*)(pf + ks * 512);
            const int ko = ks * 32 + q * 8;
#pragma unroll
            for (int mt = 0; mt < 2; ++mt) {
                bf16x8 ax = *(const bf16x8*)&Xs[(mt * 16 + lc) * SX + ko];
                aI[mt] = mfma_bf16(ax, vi, aI[mt]);
                aO[mt] = mfma_bf16(ax, vo, aO[mt]);
                aU[mt] = mfma_bf16(ax, vu, aU[mt]);
                aL[mt] = mfma_bf16(ax, vf, aL[mt]);
                aR[mt] = mfma_bf16(ax, vf, aR[mt]);
            }
        }
    }

    // ---- combine K-halves via LDS (aliases staging buffers; reads are done) ----
    __syncthreads();
    float* Rb = (float*)smem;      // 4 waves x 64 lanes x RSTR f32 = 42 KB < 70 KB
    if (kg == 1) {
        float* dst = Rb + (size_t)(s_loc * 64 + l) * RSTR;
        int o = 0;
#pragma unroll
        for (int mt = 0; mt < 2; ++mt)
#pragma unroll
            for (int r = 0; r < 4; ++r) dst[o++] = aI[mt][r];
#pragma unroll
        for (int mt = 0; mt < 2; ++mt)
#pragma unroll
            for (int r = 0; r < 4; ++r) dst[o++] = aO[mt][r];
#pragma unroll
        for (int mt = 0; mt < 2; ++mt)
#pragma unroll
            for (int r = 0; r < 4; ++r) dst[o++] = aU[mt][r];
#pragma unroll
        for (int mt = 0; mt < 2; ++mt)
#pragma unroll
            for (int r = 0; r < 4; ++r) dst[o++] = aL[mt][r];
#pragma unroll
        for (int mt = 0; mt < 2; ++mt)
#pragma unroll
            for (int r = 0; r < 4; ++r) dst[o++] = aR[mt][r];
    }
    __syncthreads();
    if (kg == 0) {
        const float* src = Rb + (size_t)(s_loc * 64 + l) * RSTR;
        int o = 0;
#pragma unroll
        for (int mt = 0; mt < 2; ++mt)
#pragma unroll
            for (int r = 0; r < 4; ++r) aI[mt][r] += src[o++];
#pragma unroll
        for (int mt = 0; mt < 2; ++mt)
#pragma unroll
            for (int r = 0; r < 4; ++r) aO[mt][r] += src[o++];
#pragma unroll
        for (int mt = 0; mt < 2; ++mt)
#pragma unroll
            for (int r = 0; r < 4; ++r) aU[mt][r] += src[o++];
#pragma unroll
        for (int mt = 0; mt < 2; ++mt)
#pragma unroll
            for (int r = 0; r < 4; ++r) aL[mt][r] += src[o++];
#pragma unroll
        for (int mt = 0; mt < 2; ++mt)
#pragma unroll
            for (int r = 0; r < 4; ++r) aR[mt][r] += src[o++];

        const int jj = s * 16 + lc;
        const float bi = b_ioux[jj]       + b_iouh[jj];
        const float bo = b_ioux[256 + jj] + b_iouh[256 + jj];
        const float bu = b_ioux[512 + jj] + b_iouh[512 + jj];
        const float bff = b_fx[jj] + b_fh[jj];
#pragma unroll
        for (int mt = 0; mt < 2; ++mt) {
#pragma unroll
            for (int r = 0; r < 4; ++r) {
                const int n = mt * 16 + q * 4 + r;
                const float iv = sigmoidf_(aI[mt][r] + bi);
                const float ov = sigmoidf_(aO[mt][r] + bo);
                const float uv = tanhfast_(aU[mt][r] + bu);
                const float fl = sigmoidf_(aL[mt][r] + bff);
                const float fr = sigmoidf_(aR[mt][r] + bff);
                float cl = 0.f, cr = 0.f;
                if (n < mcount) {
                    cl = c[(size_t)(childbase + 2 * n) * MEM + jj];
                    cr = c[(size_t)(childbase + 2 * n + 1) * MEM + jj];
                }
                const float cn = iv * uv + fl * cl + fr * cr;
                const float hn = ov * tanhfast_(cn);
                if (n < mcount) {
                    c[(size_t)(node0 + n) * MEM + jj] = cn;
                    h[(size_t)(node0 + n) * MEM + jj] = hn;
                }
            }
        }
    }
}

extern "C" void kernel_launch(void* const* d_in, const int* in_sizes, int n_in,
                              void* d_out, int out_size, void* d_ws, size_t ws_size,
                              hipStream_t stream) {
    const float* inputs = (const float*)d_in[0];
    const float* W_ioux = (const float*)d_in[1];
    const float* b_ioux = (const float*)d_in[2];
    const float* W_iouh = (const float*)d_in[3];
    const float* b_iouh = (const float*)d_in[4];
    const float* W_fx   = (const float*)d_in[5];
    const float* b_fx   = (const float*)d_in[6];
    const float* W_fh   = (const float*)d_in[7];
    const float* b_fh   = (const float*)d_in[8];

    float* out = (float*)d_out;
    float* c = out;
    float* h = out + (size_t)NNODES * MEM;

    __bf16* wtx = (__bf16*)d_ws;
    __bf16* wth = wtx + WTXF_ELEMS;

    {
        int total = WTXF_ELEMS + WTHF_ELEMS;
        hipLaunchKernelGGL(prep_weights, dim3((total + 255) / 256), dim3(256),
                           0, stream, W_ioux, W_fx, W_iouh, W_fh, (__bf16*)d_ws);
    }

    // d = 15 (leaves): x-GEMM only, 1024 blocks
    hipLaunchKernelGGL((level_mfma<true, 4>), dim3(1024), dim3(512), 0, stream,
                       inputs, wtx, wth, b_ioux, b_iouh, b_fx, b_fh, c, h,
                       (1 << 15) - 1, 1 << 15);
    // d = 14, 13: full tile kernel (GPU already saturated by block count)
    hipLaunchKernelGGL((level_mfma<false, 2>), dim3(512), dim3(512), 0, stream,
                       inputs, wtx, wth, b_ioux, b_iouh, b_fx, b_fh, c, h,
                       (1 << 14) - 1, 1 << 14);
    hipLaunchKernelGGL((level_mfma<false, 2>), dim3(256), dim3(512), 0, stream,
                       inputs, wtx, wth, b_ioux, b_iouh, b_fx, b_fh, c, h,
                       (1 << 13) - 1, 1 << 13);
    // d = 12..0: column-split kernel (4x blocks, 1/4 weight stream per block)
    for (int d = 12; d >= 0; --d) {
        int start = (1 << d) - 1;
        int sz = 1 << d;
        dim3 grid((sz + NT - 1) / NT, 4);
        hipLaunchKernelGGL(level_colsplit, grid, dim3(512), 0, stream,
                           inputs, wtx, wth, b_ioux, b_iouh, b_fx, b_fh, c, h,
                           start, sz);
    }
}